// Round 4
// baseline (49247.147 us; speedup 1.0000x reference)
//
#include <hip/hip_runtime.h>
#include <hip/hip_fp16.h>
#include <math.h>

#define BATCHN 32
#define SEQT   2048
#define NMELS  80
#define HIDN   512
#define NCLSN  64
#define BTROWS (BATCHN*SEQT)   // 65536

typedef unsigned long long u64;

__device__ inline float wave_sum(float v) {
  #pragma unroll
  for (int o = 32; o > 0; o >>= 1) v += __shfl_xor(v, o, 64);
  return v;
}
__device__ inline float ftanh(float x) {
  float ax = fabsf(x);
  float e = __expf(2.0f*ax);
  float t = 1.0f - 2.0f/(e + 1.0f);
  return copysignf(t, x);
}
__device__ inline unsigned pkh2(float a, float b) {
  __half2 h = __floats2half2_rn(a, b);
  return *(unsigned*)&h;
}
__device__ inline float2 uph2(unsigned u) {
  __half2 h = *(__half2*)&u;
  return __half22float2(h);
}
// epoch-stamped exchange word: {epoch (hi32) | f32 bits (lo32)}
__device__ inline u64 pk64(float v, unsigned ep) {
  union { float f; unsigned u; } c; c.f = v;
  return ((u64)ep << 32) | (u64)c.u;
}
__device__ inline float lo32f(u64 q) {
  union { unsigned u; float f; } c; c.u = (unsigned)q; return c.f;
}
__device__ inline void st64(u64* p, u64 v) {
  __hip_atomic_store(p, v, __ATOMIC_RELAXED, __HIP_MEMORY_SCOPE_AGENT);
}
__device__ inline u64 ld64(const u64* p) {
  return __hip_atomic_load(p, __ATOMIC_RELAXED, __HIP_MEMORY_SCOPE_AGENT);
}

// ---------------- row L2-norm: xs[m] = max(||X[m,:]||, 1e-6) ----------------
__global__ __launch_bounds__(256) void rownorm_kernel(
    const float* __restrict__ X, float* __restrict__ xs, int M, int K)
{
  int wave = threadIdx.x >> 6, lane = threadIdx.x & 63;
  int m = blockIdx.x*4 + wave;
  if (m >= M) return;
  const float* row = X + (size_t)m*K;
  float acc = 0.f;
  for (int k = lane; k < K; k += 64) { float v = row[k]; acc += v*v; }
  acc = wave_sum(acc);
  if (lane == 0) xs[m] = fmaxf(sqrtf(acc), 1e-6f);
}

// ---------------- out init: out[b,t,c] = head_b[c] ----------------
__global__ __launch_bounds__(256) void initout_kernel(
    float* __restrict__ out, const float* __restrict__ head_b)
{
  int i4 = blockIdx.x*256 + threadIdx.x;         // float4 index
  float4 v = ((const float4*)head_b)[i4 & 15];   // 64 floats = 16 float4, repeats
  ((float4*)out)[i4] = v;
}

// ---------------- fused recurrence + head, PG-only exchange ----------------
// 256 WGs = 32 batches x 8 slices of 64 h-rows, 512 threads each.
// The ONLY cross-WG data is the C1@h column-slice partials (PG), exchanged as
// epoch-stamped u64 words (gather IS the poll, 2-parity buffers,
// post-after-poll ordering makes overwrite impossible). Everything feats-only
// (be0 via per-thread B0 row in f16 regs, ||be0||, be1 row-slice, head) is
// computed WG-locally in the shadow after the PG post.
// Per step per thread: 8 polled loads + 1 store.
// __launch_bounds__(512, 1): 256-VGPR cap. R3's (512,2) capped at 128 VGPR
// and spilled the ~168-reg weight arrays to scratch (FETCH 58 GB, 4x slower).
__global__ __launch_bounds__(512, 1) void recur_kernel(
    const float* __restrict__ feats,
    const float* __restrict__ B0,
    const float* __restrict__ C1, const float* __restrict__ B1,
    const float* __restrict__ W1,
    const float* __restrict__ ltc,
    const float* __restrict__ tau0p, const float* __restrict__ gammap,
    const float* __restrict__ head_w,
    const float* __restrict__ xs0v,
    float* __restrict__ out,
    u64* __restrict__ PG)
{
  const int wg = blockIdx.x;
  const int x = wg & 7, s = (wg >> 3) & 7, qq = wg >> 6;
  const int b = x*4 + qq;        // 8 slices of batch b spread across XCDs
  const int row0 = s*64;
  const int tid = threadIdx.x;
  const int row = tid >> 3, cseg = tid & 7;   // 64 rows x 8 k-segments
  const int wid = tid >> 6, lane = tid & 63;

  __shared__ float whh_s[64*68];   // head_w[c][row0+j]      (h half)
  __shared__ float whb_s[64*68];   // head_w[c][512+row0+j]  (be1 half)
  __shared__ float er_s[512];      // full error vector
  __shared__ float bo_s[512];      // full be0 vector (next step)
  __shared__ float ft_s[80];
  __shared__ float h_s[64];        // own h slice
  __shared__ float bv_s[64];       // own be1 slice
  __shared__ float a0_s[64];
  __shared__ float red_s[8], red0_s[8];

  // ---- static weights into registers (~168 VGPRs of arrays) ----
  float c1c[64];      // C1[tid][row0+k]  (column-slice for pg partials, fp32)
  unsigned w1h[32];   // W1[row0+row][cseg*64 + rot]  f16 pairs, rotated
  unsigned b1h[32];   // B1[row0+row][cseg*64 + rot]  f16 pairs, rotated
  unsigned b0h[40];   // B0[tid][0..79]               f16 pairs
  {
    const float* src = C1 + (size_t)tid*512 + row0;
    #pragma unroll
    for (int k4 = 0; k4 < 16; k4++) {
      float4 v = *(const float4*)(src + 4*k4);
      c1c[4*k4]=v.x; c1c[4*k4+1]=v.y; c1c[4*k4+2]=v.z; c1c[4*k4+3]=v.w;
    }
  }
  {
    const float* src = W1 + (size_t)(row0 + row)*512 + cseg*64;
    #pragma unroll
    for (int j4 = 0; j4 < 16; j4++) {
      const int f = (j4 + 2*cseg) & 15;
      float4 v = *(const float4*)(src + 4*f);
      w1h[2*j4]   = pkh2(v.x, v.y);
      w1h[2*j4+1] = pkh2(v.z, v.w);
    }
  }
  {
    const float* src = B1 + (size_t)(row0 + row)*512 + cseg*64;
    #pragma unroll
    for (int j4 = 0; j4 < 16; j4++) {
      const int f = (j4 + 2*cseg) & 15;
      float4 v = *(const float4*)(src + 4*f);
      b1h[2*j4]   = pkh2(v.x, v.y);
      b1h[2*j4+1] = pkh2(v.z, v.w);
    }
  }
  {
    const float* src = B0 + (size_t)tid*80;
    #pragma unroll
    for (int j4 = 0; j4 < 20; j4++) {
      float4 v = *(const float4*)(src + 4*j4);
      b0h[2*j4]   = pkh2(v.x, v.y);
      b0h[2*j4+1] = pkh2(v.z, v.w);
    }
  }
  for (int i = tid; i < 4096; i += 512) {
    int c = i >> 6, j = i & 63;
    whh_s[c*68+j] = head_w[(size_t)c*1024 + row0 + j];
    whb_s[c*68+j] = head_w[(size_t)c*1024 + 512 + row0 + j];
  }
  if (tid < 64) {
    float xv = ltc[row0 + tid];
    float spl = (xv > 20.f) ? xv : log1pf(__expf(xv));
    a0_s[tid] = 0.1f / (1.0f + spl);
    h_s[tid] = 0.f;
  }
  const float tau0v = *tau0p, gmv = *gammap;
  __syncthreads();

  // ---- prologue: be0(0)/||be0||/be1(0) local; post PG epoch 1 (h=0 -> 0) ----
  float bev_cur, xsc, rxs_c;
  {
    const size_t bt0 = (size_t)b*SEQT;
    if (tid < 80) ft_s[tid] = feats[bt0*80 + tid];
    const float rxs00 = 1.0f / xs0v[bt0];
    __syncthreads();
    float acc = 0.f;
    #pragma unroll
    for (int j4 = 0; j4 < 20; j4++) {
      float4 fv = *(const float4*)(ft_s + 4*j4);
      float2 a = uph2(b0h[2*j4]), c2 = uph2(b0h[2*j4+1]);
      acc += a.x*fv.x + a.y*fv.y + c2.x*fv.z + c2.y*fv.w;
    }
    bev_cur = acc * rxs00;
    bo_s[tid] = bev_cur;
    float sq = wave_sum(bev_cur*bev_cur);
    if (lane == 0) red0_s[wid] = sq;
    __syncthreads();
    float xsq = red0_s[0]+red0_s[1]+red0_s[2]+red0_s[3]
              + red0_s[4]+red0_s[5]+red0_s[6]+red0_s[7];
    xsc = fmaxf(sqrtf(xsq), 1e-6f);
    rxs_c = 1.0f / xsc;
    float pbv = 0.f;
    #pragma unroll
    for (int j4 = 0; j4 < 16; j4++) {
      const int f = (j4 + 2*cseg) & 15;
      float4 ov = *(const float4*)(bo_s + cseg*64 + 4*f);
      float2 a = uph2(b1h[2*j4]), c2 = uph2(b1h[2*j4+1]);
      pbv += a.x*ov.x + a.y*ov.y + c2.x*ov.z + c2.y*ov.w;
    }
    pbv += __shfl_xor(pbv, 1, 64);
    pbv += __shfl_xor(pbv, 2, 64);
    pbv += __shfl_xor(pbv, 4, 64);
    if (cseg == 0) bv_s[row] = pbv * rxs_c;
    st64(&PG[((size_t)0*BATCHN + b)*8*512 + (size_t)s*512 + tid], pk64(0.f, 1u));
  }
  // prefetch feats(1)
  float ftn = 0.f, rxs0n = 1.f;
  {
    const size_t bt1 = (size_t)b*SEQT + 1;
    if (tid < 80) ftn = feats[bt1*80 + tid];
    rxs0n = 1.0f / xs0v[bt1];
  }
  __syncthreads();

  for (int t = 0; t < SEQT; ++t) {
    const int par = t & 1;
    const unsigned ep = (unsigned)(t + 1);

    // ---- gather-poll: 8 words, payload rides with epoch ----
    const u64* PGr = PG + ((size_t)par*BATCHN + b)*8*512;
    float g;
    {
      unsigned gg = 0;
      for (;;) {
        bool ok = true;
        float a = 0.f;
        #pragma unroll
        for (int s2 = 0; s2 < 8; s2++) {
          u64 q = ld64(&PGr[s2*512 + tid]);
          ok &= ((unsigned)(q >> 32) == ep);
          a += lo32f(q);
        }
        if (ok || ++gg > (1u<<18)) { g = a; break; }   // bail: wrong > hang
      }
    }

    // ---- error, surprise ----
    const float e = bev_cur - xsc*ftanh(g);
    er_s[tid] = e;
    float sq = wave_sum(e*e);
    if (lane == 0) red_s[wid] = sq;
    __syncthreads();                                   // B1: er_s, red_s
    const float es = red_s[0]+red_s[1]+red_s[2]+red_s[3]
                   + red_s[4]+red_s[5]+red_s[6]+red_s[7];
    const float rel = fminf(sqrtf(es)*rxs_c, 4.0f);
    const float sp = 1.0f/(1.0f + __expf(-(rel - tau0v)/gmv));

    // ---- err_eff row-slice (8 threads/row, rotated er_s reads) ----
    float ee = 0.f;
    #pragma unroll
    for (int j4 = 0; j4 < 16; j4++) {
      const int f = (j4 + 2*cseg) & 15;
      float4 ev = *(const float4*)(er_s + cseg*64 + 4*f);
      float2 a = uph2(w1h[2*j4]), c2 = uph2(w1h[2*j4+1]);
      ee += a.x*ev.x + a.y*ev.y + c2.x*ev.z + c2.y*ev.w;
    }
    ee += __shfl_xor(ee, 1, 64);
    ee += __shfl_xor(ee, 2, 64);
    ee += __shfl_xor(ee, 4, 64);
    if (cseg == 0) {
      const float hold = h_s[row];
      const float ih = 0.2f*hold + 0.6f*bv_s[row] + 0.2f*sp*ee;
      const float th = ftanh(ih);
      h_s[row] = hold + a0_s[row]*(1.0f + sp)*(th - hold);
    }
    __syncthreads();                                   // B2: h(t) ready

    // ---- pg partials for epoch t+2 (broadcast h_s reads), post ASAP ----
    if (t < SEQT-1) {
      float pg = 0.f;
      #pragma unroll
      for (int k4 = 0; k4 < 16; k4++) {
        float4 hv = *(const float4*)(h_s + 4*k4);
        pg += c1c[4*k4]*hv.x + c1c[4*k4+1]*hv.y + c1c[4*k4+2]*hv.z + c1c[4*k4+3]*hv.w;
      }
      st64(&PG[((size_t)(par^1)*BATCHN + b)*8*512 + (size_t)s*512 + tid],
           pk64(pg, (unsigned)(t+2)));
    }

    // ---- SHADOW: head(t), then feats-only state for t+1 ----
    {
      const size_t bt = (size_t)b*SEQT + t;
      const int c = row, j0 = cseg*8;
      float4 h0 = *(const float4*)(h_s + j0),  h1 = *(const float4*)(h_s + j0 + 4);
      float4 v0 = *(const float4*)(bv_s + j0), v1 = *(const float4*)(bv_s + j0 + 4);
      float4 wh0 = *(const float4*)(whh_s + c*68 + j0), wh1 = *(const float4*)(whh_s + c*68 + j0 + 4);
      float4 wb0 = *(const float4*)(whb_s + c*68 + j0), wb1 = *(const float4*)(whb_s + c*68 + j0 + 4);
      float hacc = h0.x*wh0.x + h0.y*wh0.y + h0.z*wh0.z + h0.w*wh0.w
                 + h1.x*wh1.x + h1.y*wh1.y + h1.z*wh1.z + h1.w*wh1.w
                 + v0.x*wb0.x + v0.y*wb0.y + v0.z*wb0.z + v0.w*wb0.w
                 + v1.x*wb1.x + v1.y*wb1.y + v1.z*wb1.z + v1.w*wb1.w;
      hacc += __shfl_xor(hacc, 1, 64);
      hacc += __shfl_xor(hacc, 2, 64);
      hacc += __shfl_xor(hacc, 4, 64);
      if (cseg == 0) atomicAdd(&out[bt*64 + c], hacc);
    }

    if (t < SEQT-1) {
      if (tid < 80) ft_s[tid] = ftn;
      __syncthreads();                                 // B3: ft_s; head reads done
      float acc = 0.f;
      #pragma unroll
      for (int j4 = 0; j4 < 20; j4++) {
        float4 fv = *(const float4*)(ft_s + 4*j4);
        float2 a = uph2(b0h[2*j4]), c2 = uph2(b0h[2*j4+1]);
        acc += a.x*fv.x + a.y*fv.y + c2.x*fv.z + c2.y*fv.w;
      }
      const float bevn = acc * rxs0n;
      bo_s[tid] = bevn;
      float sq2 = wave_sum(bevn*bevn);
      if (lane == 0) red0_s[wid] = sq2;
      __syncthreads();                                 // B4: bo_s, red0_s
      float xsq = red0_s[0]+red0_s[1]+red0_s[2]+red0_s[3]
                + red0_s[4]+red0_s[5]+red0_s[6]+red0_s[7];
      const float xs1n = fmaxf(sqrtf(xsq), 1e-6f);
      const float rx1n = 1.0f / xs1n;
      float pbv = 0.f;
      #pragma unroll
      for (int j4 = 0; j4 < 16; j4++) {
        const int f = (j4 + 2*cseg) & 15;
        float4 ov = *(const float4*)(bo_s + cseg*64 + 4*f);
        float2 a = uph2(b1h[2*j4]), c2 = uph2(b1h[2*j4+1]);
        pbv += a.x*ov.x + a.y*ov.y + c2.x*ov.z + c2.y*ov.w;
      }
      pbv += __shfl_xor(pbv, 1, 64);
      pbv += __shfl_xor(pbv, 2, 64);
      pbv += __shfl_xor(pbv, 4, 64);
      if (cseg == 0) bv_s[row] = pbv * rx1n;
      bev_cur = bevn; xsc = xs1n; rxs_c = rx1n;
      if (t < SEQT-2) {
        const size_t btn = (size_t)b*SEQT + (t+2);
        if (tid < 80) ftn = feats[btn*80 + tid];
        rxs0n = 1.0f / xs0v[btn];
      }
    }
  }
}

extern "C" void kernel_launch(void* const* d_in, const int* in_sizes, int n_in,
                              void* d_out, int out_size, void* d_ws, size_t ws_size,
                              hipStream_t stream)
{
  (void)in_sizes; (void)n_in; (void)out_size;
  const float* feats  = (const float*)d_in[0];
  const float* B0     = (const float*)d_in[2];
  const float* C1     = (const float*)d_in[7];
  const float* B1     = (const float*)d_in[8];
  const float* W1     = (const float*)d_in[9];
  const float* tau0_1 = (const float*)d_in[10];
  const float* gamma1 = (const float*)d_in[11];
  const float* ltc1   = (const float*)d_in[12];
  const float* head_w = (const float*)d_in[13];
  const float* head_b = (const float*)d_in[14];
  float* out = (float*)d_out;

  // ws layout: PG u64[2][32][8][512] (2 MB) | xs0 f32[65536] (256 KB)
  u64* PG  = (u64*)d_ws;
  float* xs0 = (float*)(PG + (size_t)2*BATCHN*8*HIDN);
  size_t needed = (size_t)((char*)(xs0 + BTROWS) - (char*)d_ws);
  if (ws_size < needed) return;

  rownorm_kernel<<<BTROWS/4, 256, 0, stream>>>(feats, xs0, BTROWS, NMELS);
  initout_kernel<<<(BTROWS*NCLSN/4)/256, 256, 0, stream>>>(out, head_b);
  // zero epochs so stale words can never alias epoch 1
  hipMemsetAsync(PG, 0, (size_t)2*BATCHN*8*HIDN*sizeof(u64), stream);

  void* args[] = { (void*)&feats, (void*)&B0, (void*)&C1, (void*)&B1, (void*)&W1,
                   (void*)&ltc1, (void*)&tau0_1, (void*)&gamma1, (void*)&head_w,
                   (void*)&xs0, (void*)&out, (void*)&PG };
  hipError_t e = hipLaunchCooperativeKernel((void*)recur_kernel, dim3(256), dim3(512),
                                            args, 0, stream);
  if (e != hipSuccess) {
    recur_kernel<<<256, 512, 0, stream>>>(feats, B0, C1, B1, W1, ltc1, tau0_1, gamma1,
                                          head_w, xs0, out, PG);
  }
}

// Round 5
// 10148.692 us; speedup vs baseline: 4.8526x; 4.8526x over previous
//
#include <hip/hip_runtime.h>
#include <hip/hip_fp16.h>
#include <math.h>

#define BATCHN 32
#define SEQT   2048
#define NMELS  80
#define HIDN   512
#define NCLSN  64
#define BTROWS (BATCHN*SEQT)   // 65536

typedef unsigned long long u64;
typedef _Float16 __attribute__((ext_vector_type(2))) h2v;

__device__ inline float wave_sum(float v) {
  #pragma unroll
  for (int o = 32; o > 0; o >>= 1) v += __shfl_xor(v, o, 64);
  return v;
}
__device__ inline float ftanh(float x) {
  float ax = fabsf(x);
  float e = __expf(2.0f*ax);
  float t = 1.0f - 2.0f/(e + 1.0f);
  return copysignf(t, x);
}
__device__ inline unsigned pkh2(float a, float b) {
  __half2 h = __floats2half2_rn(a, b);
  return *(unsigned*)&h;
}
// f16x2 dot with f32 accumulate: c + a.x*b.x + a.y*b.y
__device__ inline float fdot2(unsigned a, unsigned b, float c) {
#if __has_builtin(__builtin_amdgcn_fdot2)
  union { unsigned u; h2v v; } ua, ub; ua.u = a; ub.u = b;
  return __builtin_amdgcn_fdot2(ua.v, ub.v, c, false);
#else
  union { unsigned u; __half2 h; } ua, ub; ua.u = a; ub.u = b;
  float2 fa = __half22float2(ua.h), fb = __half22float2(ub.h);
  return c + fa.x*fb.x + fa.y*fb.y;
#endif
}
// epoch-stamped exchange word: {epoch (hi32) | f32 bits (lo32)}
__device__ inline u64 pk64(float v, unsigned ep) {
  union { float f; unsigned u; } c; c.f = v;
  return ((u64)ep << 32) | (u64)c.u;
}
__device__ inline float lo32f(u64 q) {
  union { unsigned u; float f; } c; c.u = (unsigned)q; return c.f;
}
__device__ inline void st64(u64* p, u64 v) {
  __hip_atomic_store(p, v, __ATOMIC_RELAXED, __HIP_MEMORY_SCOPE_AGENT);
}
__device__ inline u64 ld64(const u64* p) {
  return __hip_atomic_load(p, __ATOMIC_RELAXED, __HIP_MEMORY_SCOPE_AGENT);
}

// ---------------- row L2-norm: xs[m] = max(||X[m,:]||, 1e-6) ----------------
__global__ __launch_bounds__(256) void rownorm_kernel(
    const float* __restrict__ X, float* __restrict__ xs, int M, int K)
{
  int wave = threadIdx.x >> 6, lane = threadIdx.x & 63;
  int m = blockIdx.x*4 + wave;
  if (m >= M) return;
  const float* row = X + (size_t)m*K;
  float acc = 0.f;
  for (int k = lane; k < K; k += 64) { float v = row[k]; acc += v*v; }
  acc = wave_sum(acc);
  if (lane == 0) xs[m] = fmaxf(sqrtf(acc), 1e-6f);
}

// ---------------- out init: out[b,t,c] = head_b[c] ----------------
__global__ __launch_bounds__(256) void initout_kernel(
    float* __restrict__ out, const float* __restrict__ head_b)
{
  int i4 = blockIdx.x*256 + threadIdx.x;         // float4 index
  float4 v = ((const float4*)head_b)[i4 & 15];   // 64 floats = 16 float4, repeats
  ((float4*)out)[i4] = v;
}

// ---------------- fused recurrence + head, PG-only exchange ----------------
// 256 WGs = 32 batches x 8 slices of 64 h-rows, 256 threads each (R2-proven
// 256-VGPR config; 512-thread WGs empirically cap at 128 VGPR and spill).
// Cross-WG data: ONLY the C1@h column-slice partials (PG), epoch-stamped u64
// (gather IS the poll, 2-parity buffers, post-after-poll ordering).
// Per thread: 16 polled words, 2 posted words. All feats-only work (be0 via
// B0 in LDS, ||be0||, be1 row-slice, head) is WG-local in the shadow.
// Weight slices in f16-pair registers consumed by v_dot2_f32_f16 (f32 accum):
// c1a/c1b 64 + w1h 64 + b1h 64 = 192 array VGPRs -> no spill at 256 cap.
__global__ __launch_bounds__(256, 1) void recur_kernel(
    const float* __restrict__ feats,
    const float* __restrict__ B0,
    const float* __restrict__ C1, const float* __restrict__ B1,
    const float* __restrict__ W1,
    const float* __restrict__ ltc,
    const float* __restrict__ tau0p, const float* __restrict__ gammap,
    const float* __restrict__ head_w,
    const float* __restrict__ xs0v,
    float* __restrict__ out,
    u64* __restrict__ PG)
{
  const int wg = blockIdx.x;
  const int x = wg & 7, s = (wg >> 3) & 7, qq = wg >> 6;
  const int b = x*4 + qq;        // all 8 slices of batch b share wg%8 (XCD heuristic)
  const int row0 = s*64;
  const int tid = threadIdx.x;
  const int r = tid >> 2, kc = tid & 3;       // 64 rows x 4 col-segments
  const int wid = tid >> 6, lane = tid & 63;

  // ---- LDS ----
  __shared__ u64      b0t_s[20*512];   // B0 transposed f16x4: [k4][row] (80 KB)
  __shared__ float    whh_s[64*68];    // head_w[c][row0+j]      (h half)
  __shared__ float    whb_s[64*68];    // head_w[c][512+row0+j]  (be1 half)
  __shared__ unsigned er2_s[256];      // error f16 pairs {e[p], e[p+256]}
  __shared__ unsigned bo2_s[256];      // x_norm f16 pairs {xn[p], xn[p+256]}
  __shared__ unsigned ft2_s[40];       // feats f16 pairs
  __shared__ float    h_s[64];         // own h slice (f32, head needs it)
  __shared__ float    bv_s[64];        // own be1 slice
  __shared__ float    a0_s[64];
  __shared__ float    red_s[4], red0_s[4];

  // ---- static weights into f16-pair registers ----
  unsigned c1a[32], c1b[32];  // C1[tid][row0+2i..], C1[tid+256][row0+2i..] (adjacent pairs)
  unsigned w1h[64];           // W1[row0+r][p],[p+256] pairs, p = kc*64+u
  unsigned b1h[64];           // B1 same layout
  {
    const float* srcA = C1 + (size_t)tid*512 + row0;
    const float* srcB = C1 + (size_t)(tid+256)*512 + row0;
    #pragma unroll
    for (int j = 0; j < 16; j++) {
      float4 va = *(const float4*)(srcA + 4*j);
      float4 vb = *(const float4*)(srcB + 4*j);
      c1a[2*j] = pkh2(va.x, va.y); c1a[2*j+1] = pkh2(va.z, va.w);
      c1b[2*j] = pkh2(vb.x, vb.y); c1b[2*j+1] = pkh2(vb.z, vb.w);
    }
  }
  {
    const float* src = W1 + (size_t)(row0 + r)*512 + kc*64;
    #pragma unroll
    for (int u4 = 0; u4 < 16; u4++) {
      float4 va = *(const float4*)(src + 4*u4);
      float4 vb = *(const float4*)(src + 256 + 4*u4);
      w1h[4*u4+0] = pkh2(va.x, vb.x); w1h[4*u4+1] = pkh2(va.y, vb.y);
      w1h[4*u4+2] = pkh2(va.z, vb.z); w1h[4*u4+3] = pkh2(va.w, vb.w);
    }
  }
  {
    const float* src = B1 + (size_t)(row0 + r)*512 + kc*64;
    #pragma unroll
    for (int u4 = 0; u4 < 16; u4++) {
      float4 va = *(const float4*)(src + 4*u4);
      float4 vb = *(const float4*)(src + 256 + 4*u4);
      b1h[4*u4+0] = pkh2(va.x, vb.x); b1h[4*u4+1] = pkh2(va.y, vb.y);
      b1h[4*u4+2] = pkh2(va.z, vb.z); b1h[4*u4+3] = pkh2(va.w, vb.w);
    }
  }
  // B0 -> LDS transposed: b0t[k4*512 + row] = f16x4 of B0[row][4k4..4k4+3]
  for (int i = tid; i < 20*512; i += 256) {
    int k4 = i >> 9, row = i & 511;
    float4 v = *(const float4*)(B0 + (size_t)row*80 + 4*k4);
    b0t_s[i] = (u64)pkh2(v.x, v.y) | ((u64)pkh2(v.z, v.w) << 32);
  }
  for (int i = tid; i < 4096; i += 256) {
    int c = i >> 6, j = i & 63;
    whh_s[c*68+j] = head_w[(size_t)c*1024 + row0 + j];
    whb_s[c*68+j] = head_w[(size_t)c*1024 + 512 + row0 + j];
  }
  if (tid < 64) {
    float xv = ltc[row0 + tid];
    float spl = (xv > 20.f) ? xv : log1pf(__expf(xv));
    a0_s[tid] = 0.1f / (1.0f + spl);
    h_s[tid] = 0.f;
  }
  const float tau0v = *tau0p, gmv = *gammap;
  __syncthreads();

  // persistent per-step feats-only state
  float bev0 = 0.f, bev1 = 0.f, xsc = 1.f, rxs_c = 1.f;
  float ftn = 0.f, rxs0n = 1.f;

  // shadow: be0 / ||be0|| / be1 slice for the NEXT step, from staged ftn/rxs0n.
  auto shadow = [&]() {
    float fo = __shfl_xor(ftn, 1, 64);
    if (tid < 80 && (tid & 1) == 0) ft2_s[tid >> 1] = pkh2(ftn, fo);
    __syncthreads();                              // S1: ft2 ready (also fences er2/red reads)
    float a0v = 0.f, a1v = 0.f;
    #pragma unroll
    for (int k4 = 0; k4 < 20; k4++) {
      unsigned fA = ft2_s[2*k4], fB = ft2_s[2*k4+1];
      u64 qa = b0t_s[k4*512 + tid];
      u64 qb = b0t_s[k4*512 + tid + 256];
      a0v = fdot2((unsigned)qa, fA, a0v); a0v = fdot2((unsigned)(qa >> 32), fB, a0v);
      a1v = fdot2((unsigned)qb, fA, a1v); a1v = fdot2((unsigned)(qb >> 32), fB, a1v);
    }
    const float b0n = a0v * rxs0n, b1n = a1v * rxs0n;
    float sq = wave_sum(b0n*b0n + b1n*b1n);
    if (lane == 0) red0_s[wid] = sq;
    __syncthreads();                              // S2: red0 ready
    const float xsq = red0_s[0]+red0_s[1]+red0_s[2]+red0_s[3];
    const float xs1n = fmaxf(sqrtf(xsq), 1e-6f);
    const float rx1n = 1.0f / xs1n;
    bo2_s[tid] = pkh2(b0n*rx1n, b1n*rx1n);        // x_norm pairs (clip is a no-op)
    __syncthreads();                              // S3: bo2 ready
    float pb = 0.f;
    #pragma unroll
    for (int u4 = 0; u4 < 16; u4++) {
      uint4 ov = *(const uint4*)(bo2_s + kc*64 + 4*u4);
      pb = fdot2(b1h[4*u4+0], ov.x, pb);
      pb = fdot2(b1h[4*u4+1], ov.y, pb);
      pb = fdot2(b1h[4*u4+2], ov.z, pb);
      pb = fdot2(b1h[4*u4+3], ov.w, pb);
    }
    pb += __shfl_xor(pb, 1, 64);
    pb += __shfl_xor(pb, 2, 64);
    if (kc == 0) bv_s[r] = pb;                    // be1 (normalized input already)
    bev0 = b0n; bev1 = b1n; xsc = xs1n; rxs_c = rx1n;
  };

  // ---- prologue: state for t=0; post PG epoch 1 (h=0 -> zeros) ----
  {
    const size_t bt0 = (size_t)b*SEQT;
    if (tid < 80) ftn = feats[bt0*80 + tid];
    rxs0n = 1.0f / xs0v[bt0];
    shadow();
    u64* PGw = PG + ((size_t)0*BATCHN + b)*8*512 + (size_t)s*512;
    st64(&PGw[tid],       pk64(0.f, 1u));
    st64(&PGw[tid + 256], pk64(0.f, 1u));
  }
  // stage feats(1)
  {
    const size_t bt1 = (size_t)b*SEQT + 1;
    ftn = (tid < 80) ? feats[bt1*80 + tid] : 0.f;
    rxs0n = 1.0f / xs0v[bt1];
  }
  __syncthreads();

  for (int t = 0; t < SEQT; ++t) {
    const int par = t & 1;
    const unsigned ep = (unsigned)(t + 1);

    // ---- gather-poll: 16 words (parallel loads), payload rides with epoch ----
    const u64* PGr = PG + ((size_t)par*BATCHN + b)*8*512;
    float g0, g1;
    {
      unsigned gg = 0;
      for (;;) {
        bool ok = true;
        float a0 = 0.f, a1 = 0.f;
        #pragma unroll
        for (int s2 = 0; s2 < 8; s2++) {
          u64 q  = ld64(&PGr[s2*512 + tid]);
          u64 q2 = ld64(&PGr[s2*512 + tid + 256]);
          ok &= ((unsigned)(q  >> 32) == ep);
          ok &= ((unsigned)(q2 >> 32) == ep);
          a0 += lo32f(q); a1 += lo32f(q2);
        }
        if (ok || ++gg > (1u<<18)) { g0 = a0; g1 = a1; break; }  // bail: wrong > hang
      }
    }

    // ---- error, surprise ----
    const float e0 = bev0 - xsc*ftanh(g0);
    const float e1 = bev1 - xsc*ftanh(g1);
    er2_s[tid] = pkh2(e0, e1);
    float es = wave_sum(e0*e0 + e1*e1);
    if (lane == 0) red_s[wid] = es;
    __syncthreads();                               // B1: er2, red ready
    const float ess = red_s[0]+red_s[1]+red_s[2]+red_s[3];
    const float rel = fminf(sqrtf(ess)*rxs_c, 4.0f);
    const float sp = 1.0f/(1.0f + __expf(-(rel - tau0v)/gmv));

    // ---- err_eff row-slice: 64 dot2 over {e[p],e[p+256]} pairs ----
    float ee = 0.f;
    #pragma unroll
    for (int u4 = 0; u4 < 16; u4++) {
      uint4 ev = *(const uint4*)(er2_s + kc*64 + 4*u4);
      ee = fdot2(w1h[4*u4+0], ev.x, ee);
      ee = fdot2(w1h[4*u4+1], ev.y, ee);
      ee = fdot2(w1h[4*u4+2], ev.z, ee);
      ee = fdot2(w1h[4*u4+3], ev.w, ee);
    }
    ee += __shfl_xor(ee, 1, 64);
    ee += __shfl_xor(ee, 2, 64);
    if (kc == 0) {
      const float hold = h_s[r];
      const float ih = 0.2f*hold + 0.6f*bv_s[r] + 0.2f*sp*ee;
      const float th = ftanh(ih);
      h_s[r] = hold + a0_s[r]*(1.0f + sp)*(th - hold);
    }
    __syncthreads();                               // B2: h(t) ready

    // ---- pg partials for epoch t+2, post ASAP (critical path ends here) ----
    if (t < SEQT-1) {
      float p0 = 0.f, p1 = 0.f;
      #pragma unroll
      for (int j = 0; j < 16; j++) {
        float4 hv = *(const float4*)(h_s + 4*j);
        unsigned hA = pkh2(hv.x, hv.y), hB = pkh2(hv.z, hv.w);
        p0 = fdot2(c1a[2*j],   hA, p0);
        p0 = fdot2(c1a[2*j+1], hB, p0);
        p1 = fdot2(c1b[2*j],   hA, p1);
        p1 = fdot2(c1b[2*j+1], hB, p1);
      }
      u64* PGw = PG + ((size_t)(par^1)*BATCHN + b)*8*512 + (size_t)s*512;
      st64(&PGw[tid],       pk64(p0, ep + 1u));
      st64(&PGw[tid + 256], pk64(p1, ep + 1u));
    }

    // ---- SHADOW: head(t), then feats-only state for t+1 ----
    {
      const size_t bt = (size_t)b*SEQT + t;
      const int c = r, j0 = kc*16;
      float hacc = 0.f;
      #pragma unroll
      for (int j4 = 0; j4 < 4; j4++) {
        float4 hv4 = *(const float4*)(h_s  + j0 + 4*j4);
        float4 bv4 = *(const float4*)(bv_s + j0 + 4*j4);
        float4 wh  = *(const float4*)(whh_s + c*68 + j0 + 4*j4);
        float4 wb  = *(const float4*)(whb_s + c*68 + j0 + 4*j4);
        hacc += hv4.x*wh.x + hv4.y*wh.y + hv4.z*wh.z + hv4.w*wh.w
              + bv4.x*wb.x + bv4.y*wb.y + bv4.z*wb.z + bv4.w*wb.w;
      }
      hacc += __shfl_xor(hacc, 1, 64);
      hacc += __shfl_xor(hacc, 2, 64);
      if (kc == 0) atomicAdd(&out[bt*64 + c], hacc);
    }
    if (t < SEQT-1) {
      shadow();                                    // state for t+1 (3 barriers inside)
      if (t < SEQT-2) {
        const size_t btn = (size_t)b*SEQT + (t+2);
        if (tid < 80) ftn = feats[btn*80 + tid];
        rxs0n = 1.0f / xs0v[btn];
      }
    }
  }
}

extern "C" void kernel_launch(void* const* d_in, const int* in_sizes, int n_in,
                              void* d_out, int out_size, void* d_ws, size_t ws_size,
                              hipStream_t stream)
{
  (void)in_sizes; (void)n_in; (void)out_size;
  const float* feats  = (const float*)d_in[0];
  const float* B0     = (const float*)d_in[2];
  const float* C1     = (const float*)d_in[7];
  const float* B1     = (const float*)d_in[8];
  const float* W1     = (const float*)d_in[9];
  const float* tau0_1 = (const float*)d_in[10];
  const float* gamma1 = (const float*)d_in[11];
  const float* ltc1   = (const float*)d_in[12];
  const float* head_w = (const float*)d_in[13];
  const float* head_b = (const float*)d_in[14];
  float* out = (float*)d_out;

  // ws layout: PG u64[2][32][8][512] (2 MB) | xs0 f32[65536] (256 KB)
  u64* PG  = (u64*)d_ws;
  float* xs0 = (float*)(PG + (size_t)2*BATCHN*8*HIDN);
  size_t needed = (size_t)((char*)(xs0 + BTROWS) - (char*)d_ws);
  if (ws_size < needed) return;

  rownorm_kernel<<<BTROWS/4, 256, 0, stream>>>(feats, xs0, BTROWS, NMELS);
  initout_kernel<<<(BTROWS*NCLSN/4)/256, 256, 0, stream>>>(out, head_b);
  // zero epochs so stale words can never alias epoch 1
  hipMemsetAsync(PG, 0, (size_t)2*BATCHN*8*HIDN*sizeof(u64), stream);

  void* args[] = { (void*)&feats, (void*)&B0, (void*)&C1, (void*)&B1, (void*)&W1,
                   (void*)&ltc1, (void*)&tau0_1, (void*)&gamma1, (void*)&head_w,
                   (void*)&xs0, (void*)&out, (void*)&PG };
  hipError_t e = hipLaunchCooperativeKernel((void*)recur_kernel, dim3(256), dim3(256),
                                            args, 0, stream);
  if (e != hipSuccess) {
    recur_kernel<<<256, 256, 0, stream>>>(feats, B0, C1, B1, W1, ltc1, tau0_1, gamma1,
                                          head_w, xs0, out, PG);
  }
}